// Round 7
// baseline (254.298 us; speedup 1.0000x reference)
//
#include <hip/hip_runtime.h>

// Problem constants (from reference): B=64, T=512, D=41
#define BB 64
#define TT 512
#define DD 41
#define LL (TT * DD)          // 20992
#define COLS (DD + 3)         // 44
#define F4R (COLS / 4)        // 11
#define TILE 256
#define TPB (LL / TILE)       // 82 tiles per batch row (exact)
#define NTILES (BB * TPB)     // 5248

typedef float f4v __attribute__((ext_vector_type(4)));  // native vector
typedef unsigned long long u64;

// Workspace layout: bitmap u64[NTILES*4] (168 KB) | tileOff int[NTILES] | nObs int[BB]

// ---------------------------------------------------------------------------
// KA: fused per-row count + scan. One block per batch row (64 x 256).
// Wave w handles tile it*4+w: 4 stride-64 dword loads; ballot j is exactly
// the 64-elem bitmap word KB's wave j needs. Then block-scan of 82 counts.
// ---------------------------------------------------------------------------
__global__ __launch_bounds__(256)
void kA_count_scan(const int* __restrict__ mask, u64* __restrict__ bitmap,
                   int* __restrict__ tileOff, int* __restrict__ nObs) {
    const int b    = blockIdx.x;
    const int tid  = threadIdx.x;
    const int w    = tid >> 6;
    const int lane = tid & 63;
    const int* mrow = mask + (size_t)b * LL;

    __shared__ int cnts[TPB];
    __shared__ int s[256];

    for (int it = 0; it < 21; ++it) {
        const int tile = it * 4 + w;               // wave-uniform
        if (tile < TPB) {
            u64 bal[4];
            int cnt = 0;
#pragma unroll
            for (int j = 0; j < 4; ++j) {
                const int m = mrow[tile * TILE + j * 64 + lane];  // coalesced 256B
                bal[j] = __ballot(m != 0);
                cnt += __popcll(bal[j]);
            }
            if (lane == 0) {
#pragma unroll
                for (int j = 0; j < 4; ++j)
                    bitmap[(size_t)(b * TPB + tile) * 4 + j] = bal[j];
                cnts[tile] = cnt;
            }
        }
    }
    __syncthreads();

    const int v = (tid < TPB) ? cnts[tid] : 0;
    s[tid] = v;
    __syncthreads();
    for (int off = 1; off < 256; off <<= 1) {      // Hillis–Steele inclusive
        const int t = (tid >= off) ? s[tid - off] : 0;
        __syncthreads();
        s[tid] += t;
        __syncthreads();
    }
    if (tid < TPB) tileOff[b * TPB + tid] = s[tid] - v;   // exclusive
    if (tid == 0)  nObs[b] = s[TPB - 1];                  // row total
}

// ---------------------------------------------------------------------------
// KB: emit. Block = one contiguous SOURCE tile of 256 elems. Mask-free:
// m/rank/counts derived from 4 broadcast bitmap words (no ballot, no wsum
// LDS, one barrier only). Staging + 11 coalesced f4 sweeps as verified in R6.
// ---------------------------------------------------------------------------
__global__ __launch_bounds__(TILE)
void kB_emit(const float* __restrict__ target_x, const float* __restrict__ vals,
             const u64* __restrict__ bitmap, const int* __restrict__ tileOff,
             const int* __restrict__ nObs, float* __restrict__ out) {
    const int blk = blockIdx.x;               // flat tile index
    const int tid = threadIdx.x;
    const int b     = blk / TPB;
    const int lrow0 = (blk - b * TPB) * TILE; // base index within batch row
    const int w     = tid >> 6;
    const int lane  = tid & 63;

    const u64 b0 = bitmap[(size_t)blk * 4 + 0];   // broadcast loads
    const u64 b1 = bitmap[(size_t)blk * 4 + 1];
    const u64 b2 = bitmap[(size_t)blk * 4 + 2];
    const u64 b3 = bitmap[(size_t)blk * 4 + 3];
    const u64 mybal = (w == 0) ? b0 : (w == 1) ? b1 : (w == 2) ? b2 : b3;

    const int m = (int)((mybal >> lane) & 1ull);
    const int p0 = __popcll(b0), p1 = __popcll(b1), p2 = __popcll(b2), p3 = __popcll(b3);
    const int cntObs = p0 + p1 + p2 + p3;
    const int wbase  = (w > 0 ? p0 : 0) + (w > 1 ? p1 : 0) + (w > 2 ? p2 : 0);
    const int eObs   = wbase + __popcll(mybal & ((1ull << lane) - 1ull));
    const int d = m ? eObs : cntObs + (tid - eObs);   // local packed dest (perm)

    const float Uraw = vals[(size_t)blk * TILE + tid];  // coalesced
    const int lrow = lrow0 + tid;
    const int t  = lrow / DD;                 // magic-mul
    const int ch = lrow - t * DD;
    const float tau = target_x[b * TT + t];   // 2 KB row table, L1-hot

    __shared__ f4v info[TILE];                // {tau_p, U_p, ch(bits), vm}
    f4v inf;
    inf.x = m ? tau : 0.0f;
    inf.y = m ? Uraw : 0.0f;
    inf.z = __int_as_float(m ? ch : 0);
    inf.w = m ? 1.0f : 0.0f;
    info[d] = inf;
    __syncthreads();

    // ---- dest runs: observed rows then padded rows (both contiguous) ----
    const int tOff    = tileOff[blk];                  // obs before this tile (row-local)
    const int padRow0 = nObs[b] + (lrow0 - tOff);      // pads before this tile
    const size_t rowBase = (size_t)b * LL;

    f4v* outp = reinterpret_cast<f4v*>(out);
#pragma unroll
    for (int k = 0; k < F4R; ++k) {
        const int q  = k * TILE + tid;        // tile-local f4 index
        const int rr = q / F4R;               // local row
        const int c4 = q - rr * F4R;          // f4-column
        const f4v v = info[rr];               // broadcast ds_read_b128
        const int chh = __float_as_int(v.z);
        const int gr = (rr < cntObs) ? (tOff + rr) : (padRow0 + (rr - cntObs));
        const int c0 = c4 * 4;
        f4v rv;
#pragma unroll
        for (int j = 0; j < 4; ++j) {
            const int c = c0 + j;
            float x;
            if (c == 0)            x = v.x;                          // tau_p
            else if (c <= DD)      x = (c - 1 == chh) ? 1.0f : 0.0f; // one_hot(C_p)
            else if (c == DD + 1)  x = v.y;                          // U_p
            else                   x = v.w;                          // valid flag
            rv[j] = x;
        }
        outp[(rowBase + (size_t)gr) * F4R + c4] = rv;   // coalesced within runs
    }
}

extern "C" void kernel_launch(void* const* d_in, const int* in_sizes, int n_in,
                              void* d_out, int out_size, void* d_ws, size_t ws_size,
                              hipStream_t stream) {
    const float* target_x = (const float*)d_in[0];  // [B, T]
    const float* vals     = (const float*)d_in[1];  // [B, T, D]
    const int*   mask     = (const int*)d_in[2];    // [B, T, D]
    float* out = (float*)d_out;                     // [B, L, D+3]

    u64* bitmap  = (u64*)d_ws;                      // [NTILES*4] = 168 KB
    int* tileOff = (int*)(bitmap + (size_t)NTILES * 4);  // [NTILES]
    int* nObs    = tileOff + NTILES;                // [BB]

    kA_count_scan<<<BB, 256, 0, stream>>>(mask, bitmap, tileOff, nObs);
    kB_emit<<<NTILES, TILE, 0, stream>>>(target_x, vals, bitmap, tileOff, nObs, out);
}